// Round 2
// baseline (556.916 us; speedup 1.0000x reference)
//
#include <hip/hip_runtime.h>
#include <cmath>

typedef __bf16 bfx8 __attribute__((ext_vector_type(8)));
typedef float f32x4 __attribute__((ext_vector_type(4)));
typedef unsigned short u16x8 __attribute__((ext_vector_type(8)));

static constexpr int BB = 4, SS = 2048, DD = 2048;

__device__ __forceinline__ unsigned short f2bf(float f) {
  unsigned u = __builtin_bit_cast(unsigned, f);
  u += 0x7fffu + ((u >> 16) & 1u);
  return (unsigned short)(u >> 16);
}

// global->LDS async copy, 16B per lane. LDS dest must be wave-uniform base;
// HW adds lane*16.
__device__ __forceinline__ void gload_lds16(const void* g, void* l) {
  __builtin_amdgcn_global_load_lds(
      (__attribute__((address_space(1))) unsigned int*)(g),
      (__attribute__((address_space(3))) unsigned int*)(l),
      16, 0, 0);
}

// -------------------------------------------------------------------------
// C[M,N] = A[M,K] * B_t[N,K]  (bf16 in, fp32 acc). 128x128 tile, BK=64,
// 4 waves (2x2), mfma_f32_16x16x32_bf16, swizzled LDS (rule 21: linear LDS
// dest + inverse-swizzled global source + swizzled ds_read).
// CMODE 0: bf16 out row-major        (QKV q,k)
// CMODE 1: f32 out * scale, skip blocks fully above diagonal (scores)
// CMODE 2: f32 out, K-tiles limited to diagonal (PV)
// CMODE 3: bf16 out TRANSPOSED per batch -> vt[b][n][s] (V projection)
// -------------------------------------------------------------------------
template <int CMODE>
__global__ __launch_bounds__(256) void gemm_bt(
    const unsigned short* __restrict__ A, const unsigned short* __restrict__ B,
    void* __restrict__ Cv, int N, int K,
    long long sA, long long sB, long long sC, float scale)
{
  const int bx = blockIdx.x, by = blockIdx.y, bz = blockIdx.z;
  if (CMODE == 1 && bx > by) return;  // fully above causal diagonal
  const int t = threadIdx.x;
  const int wave = t >> 6, lane = t & 63;
  const int fr = lane & 15, fk = lane >> 4;
  const int m0 = by << 7, n0 = bx << 7;

  __shared__ __align__(16) char lds[32768];  // A tile 16KB + B tile 16KB

  const unsigned short* Ab = A + (size_t)bz * sA;
  const unsigned short* Bb = B + (size_t)bz * sB;

  // staging: thread t covers 16B chunks c = i*256+t; LDS linear, global
  // source column pre-swizzled (involution) so swizzled reads see A[row][k].
  const unsigned short* aSrc[4];
  const unsigned short* bSrc[4];
  int ldsOff[4];
#pragma unroll
  for (int i = 0; i < 4; ++i) {
    int c = i * 256 + t;
    int row = c >> 3;                                // 128B (=BK*2) per row
    int scb = ((c & 7) << 4) ^ ((row & 7) << 4);     // swizzled byte col
    aSrc[i] = Ab + (size_t)(m0 + row) * K + (scb >> 1);
    bSrc[i] = Bb + (size_t)(n0 + row) * K + (scb >> 1);
    ldsOff[i] = i * 4096 + wave * 1024;              // wave-uniform base
  }

  int ktiles = K >> 6;
  if (CMODE == 2) ktiles = min(ktiles, (by + 1) * 2);  // P==0 past diagonal

  f32x4 acc[4][4] = {};
  const int wr = (wave >> 1) << 6;
  const int wc = (wave & 1) << 6;
  const int sx = (fr & 7) << 4;  // read-side swizzle (row&7 == fr&7 here)

  for (int kt = 0; kt < ktiles; ++kt) {
    __syncthreads();  // previous compute done before overwrite
#pragma unroll
    for (int i = 0; i < 4; ++i) {
      gload_lds16(aSrc[i], &lds[ldsOff[i]]);
      gload_lds16(bSrc[i], &lds[16384 + ldsOff[i]]);
      aSrc[i] += 64;
      bSrc[i] += 64;
    }
    __syncthreads();  // compiler drains vmcnt(0) here
#pragma unroll
    for (int kk = 0; kk < 2; ++kk) {
      bfx8 af[4], bfv[4];
#pragma unroll
      for (int mi = 0; mi < 4; ++mi) {
        int ar = wr + mi * 16 + fr;
        af[mi] = *(const bfx8*)&lds[ar * 128 + ((kk * 64 + fk * 16) ^ sx)];
      }
#pragma unroll
      for (int ni = 0; ni < 4; ++ni) {
        int br = wc + ni * 16 + fr;
        bfv[ni] = *(const bfx8*)&lds[16384 + br * 128 + ((kk * 64 + fk * 16) ^ sx)];
      }
#pragma unroll
      for (int mi = 0; mi < 4; ++mi)
#pragma unroll
        for (int ni = 0; ni < 4; ++ni)
          acc[mi][ni] = __builtin_amdgcn_mfma_f32_16x16x32_bf16(
              af[mi], bfv[ni], acc[mi][ni], 0, 0, 0);
    }
  }

  // epilogue: C/D layout col=lane&15, row=(lane>>4)*4+reg (m89-verified)
#pragma unroll
  for (int mi = 0; mi < 4; ++mi) {
#pragma unroll
    for (int ni = 0; ni < 4; ++ni) {
      int r0 = m0 + wr + mi * 16 + fk * 4;
      int cn = n0 + wc + ni * 16 + fr;
      if (CMODE == 0) {
        unsigned short* C = (unsigned short*)Cv + (size_t)bz * sC;
#pragma unroll
        for (int j = 0; j < 4; ++j)
          C[(size_t)(r0 + j) * N + cn] = f2bf(acc[mi][ni][j]);
      } else if (CMODE == 1 || CMODE == 2) {
        float* C = (float*)Cv + (size_t)bz * sC;
#pragma unroll
        for (int j = 0; j < 4; ++j)
          C[(size_t)(r0 + j) * N + cn] = acc[mi][ni][j] * scale;
      } else {  // CMODE 3: vt[b][d][s], 4 consecutive s per lane
        unsigned short* VT = (unsigned short*)Cv;
        int b = r0 >> 11, s0v = r0 & 2047;
        ushort4 pk;
        pk.x = f2bf(acc[mi][ni][0]);
        pk.y = f2bf(acc[mi][ni][1]);
        pk.z = f2bf(acc[mi][ni][2]);
        pk.w = f2bf(acc[mi][ni][3]);
        *(ushort4*)&VT[(size_t)b * DD * SS + (size_t)cn * SS + s0v] = pk;
      }
    }
  }
}

// x fp32 -> bf16, 8 elements/thread
__global__ __launch_bounds__(256) void cvt_x_kernel(
    const float* __restrict__ x, unsigned short* __restrict__ xb)
{
  size_t i = ((size_t)blockIdx.x * 256 + threadIdx.x) * 8;
  float4 a = *(const float4*)(x + i);
  float4 b = *(const float4*)(x + i + 4);
  u16x8 o = {f2bf(a.x), f2bf(a.y), f2bf(a.z), f2bf(a.w),
             f2bf(b.x), f2bf(b.y), f2bf(b.z), f2bf(b.w)};
  *(u16x8*)(xb + i) = o;
}

// W [K][N] fp32 -> Wt [N][K] bf16, 64x64 LDS tile transpose; z picks Wq/Wk/Wv
__global__ __launch_bounds__(256) void cvt_wT_kernel(
    const float* __restrict__ Wq, const float* __restrict__ Wk,
    const float* __restrict__ Wv, unsigned short* __restrict__ Wt)
{
  const float* W = blockIdx.z == 0 ? Wq : (blockIdx.z == 1 ? Wk : Wv);
  unsigned short* out = Wt + (size_t)blockIdx.z * DD * DD;
  __shared__ unsigned short tile[64][65];
  int k0 = blockIdx.y * 64, n0 = blockIdx.x * 64;
#pragma unroll
  for (int i = 0; i < 16; ++i) {
    int idx = threadIdx.x + i * 256;
    int r = idx >> 6, c = idx & 63;
    tile[r][c] = f2bf(W[(size_t)(k0 + r) * DD + n0 + c]);
  }
  __syncthreads();
#pragma unroll
  for (int i = 0; i < 16; ++i) {
    int idx = threadIdx.x + i * 256;
    int r = idx >> 6, c = idx & 63;
    out[(size_t)(n0 + r) * DD + k0 + c] = tile[c][r];
  }
}

// causal row softmax: scores fp32 [b][i][:] -> P bf16 (zeros for j>i)
__global__ __launch_bounds__(256) void softmax_causal(
    const float* __restrict__ Sc, unsigned short* __restrict__ P)
{
  const int i = blockIdx.x, b = blockIdx.y, t = threadIdx.x;
  const float* srow = Sc + ((size_t)b * SS + i) * SS;
  unsigned short* prow = P + ((size_t)b * SS + i) * SS;
  const int j0 = t * 8;
  float4 v0 = *(const float4*)(srow + j0);
  float4 v1 = *(const float4*)(srow + j0 + 4);
  float s[8] = {v0.x, v0.y, v0.z, v0.w, v1.x, v1.y, v1.z, v1.w};
  float mx = -INFINITY;
#pragma unroll
  for (int e = 0; e < 8; ++e) {
    if (j0 + e > i) s[e] = -INFINITY;
    mx = fmaxf(mx, s[e]);
  }
#pragma unroll
  for (int off = 32; off; off >>= 1) mx = fmaxf(mx, __shfl_xor(mx, off));
  __shared__ float red[8];
  if ((t & 63) == 0) red[t >> 6] = mx;
  __syncthreads();
  mx = fmaxf(fmaxf(red[0], red[1]), fmaxf(red[2], red[3]));
  float e8[8];
  float sm = 0.f;
#pragma unroll
  for (int e = 0; e < 8; ++e) {
    e8[e] = (j0 + e <= i) ? __expf(s[e] - mx) : 0.f;
    sm += e8[e];
  }
#pragma unroll
  for (int off = 32; off; off >>= 1) sm += __shfl_xor(sm, off);
  if ((t & 63) == 0) red[4 + (t >> 6)] = sm;
  __syncthreads();
  float inv = 1.0f / (red[4] + red[5] + red[6] + red[7]);
  u16x8 o;
#pragma unroll
  for (int e = 0; e < 8; ++e) o[e] = f2bf(e8[e] * inv);
  *(u16x8*)(prow + j0) = o;
}

extern "C" void kernel_launch(void* const* d_in, const int* in_sizes, int n_in,
                              void* d_out, int out_size, void* d_ws, size_t ws_size,
                              hipStream_t stream)
{
  const float* x  = (const float*)d_in[0];
  const float* Wq = (const float*)d_in[1];
  const float* Wk = (const float*)d_in[2];
  const float* Wv = (const float*)d_in[3];
  float* out = (float*)d_out;

  const size_t MR = (size_t)BB * SS;  // 8192 rows
  unsigned short* xb = (unsigned short*)d_ws;     // [8192][2048] bf16
  unsigned short* Wt = xb + MR * DD;              // 3 x [2048][2048] bf16 (W^T)
  unsigned short* qk = Wt + 3ull * DD * DD;       // q,k each [8192][2048] bf16
  unsigned short* vt = qk + 2ull * MR * DD;       // [4][2048 d][2048 s] bf16
  float* sc = (float*)(vt + (size_t)BB * DD * SS);       // [4][2048][2048] f32
  unsigned short* P = (unsigned short*)(sc + (size_t)BB * SS * SS);  // bf16

  cvt_x_kernel<<<dim3(8192), 256, 0, stream>>>(x, xb);
  cvt_wT_kernel<<<dim3(32, 32, 3), 256, 0, stream>>>(Wq, Wk, Wv, Wt);

  // Q,K projections: [8192,2048] x Wt[N,K], z in {0,1}
  gemm_bt<0><<<dim3(16, 64, 2), 256, 0, stream>>>(
      xb, Wt, qk, DD, DD, 0, (long long)DD * DD, (long long)(MR * DD), 1.f);
  // V projection, transposed epilogue -> vt[b][d][s]
  gemm_bt<3><<<dim3(16, 64, 1), 256, 0, stream>>>(
      xb, Wt + 2ull * DD * DD, vt, DD, DD, 0, 0, 0, 1.f);

  // scores[b] = q[b] k[b]^T * 1/sqrt(D), fp32, causal block skip
  const float iscale = 1.0f / sqrtf((float)DD);
  gemm_bt<1><<<dim3(16, 16, 4), 256, 0, stream>>>(
      qk, qk + MR * DD, sc, SS, DD,
      (long long)(SS * (size_t)DD), (long long)(SS * (size_t)DD),
      (long long)(SS * (size_t)SS), iscale);

  softmax_causal<<<dim3(SS, BB), 256, 0, stream>>>(sc, P);

  // out[b] = P[b] vt[b]^T, fp32, K-tiles limited to diagonal
  gemm_bt<2><<<dim3(16, 16, 4), 256, 0, stream>>>(
      P, vt, out, DD, SS,
      (long long)(SS * (size_t)SS), (long long)(DD * (size_t)SS),
      (long long)(SS * (size_t)DD), 1.f);
}

// Round 4
// 506.888 us; speedup vs baseline: 1.0987x; 1.0987x over previous
//
#include <hip/hip_runtime.h>
#include <cmath>

typedef __bf16 bfx8 __attribute__((ext_vector_type(8)));
typedef float f32x4 __attribute__((ext_vector_type(4)));
typedef unsigned short u16x8 __attribute__((ext_vector_type(8)));

static constexpr int BB = 4, SS = 2048, DD = 2048;

__device__ __forceinline__ unsigned short f2bf(float f) {
  unsigned u = __builtin_bit_cast(unsigned, f);
  u += 0x7fffu + ((u >> 16) & 1u);
  return (unsigned short)(u >> 16);
}

// global->LDS async copy, 16B per lane. LDS dest wave-uniform; HW adds lane*16.
__device__ __forceinline__ void gload_lds16(const void* g, void* l) {
  __builtin_amdgcn_global_load_lds(
      (__attribute__((address_space(1))) unsigned int*)(g),
      (__attribute__((address_space(3))) unsigned int*)(l),
      16, 0, 0);
}

// -------------------------------------------------------------------------
// C[M,N] = A[M,K] * B_t[N,K] (bf16 in, fp32 acc). 256x256 tile, BK=64,
// 8 waves (2M x 4N), 4-phase pipelined K-loop (8-phase template / 2 K-tiles),
// double-buffered 2x64KB LDS, XOR-swizzle (rule 21: linear LDS dest +
// inverse-swizzled global source + swizzled ds_read). Counted-latency drain:
// next tile staged in phases 0-1, vmcnt(0) only at end of phase 3.
// CMODE 0: bf16 out row-major
// CMODE 1: f32 out * scale, skip blocks fully above causal diagonal
// CMODE 2: f32 out, K-tiles truncated at the causal diagonal
// -------------------------------------------------------------------------
template <int CMODE>
__global__ __launch_bounds__(512, 2) void gemm_bt(
    const unsigned short* __restrict__ A, const unsigned short* __restrict__ B,
    void* __restrict__ Cv, int N, int K,
    long long sA, long long sB, long long sC, float scale)
{
  const int bx = blockIdx.x, by = blockIdx.y, bz = blockIdx.z;
  if (CMODE == 1 && bx > by) return;  // fully above causal diagonal
  const int t = threadIdx.x;
  const int wave = t >> 6, lane = t & 63;
  const int fr = lane & 15, fk = lane >> 4;
  const int wr = wave >> 2;           // M half   (0..1)
  const int wc = wave & 3;            // N quarter (0..3)
  const int m0 = by << 8, n0 = bx << 8;

  __shared__ __align__(16) char lds[131072];  // 2 bufs x (A 32KB + B 32KB)

  const unsigned short* Ab = A + (size_t)bz * sA;
  const unsigned short* Bb = B + (size_t)bz * sB;

  // Staging: thread t covers 16B chunks c = (j>>1)*1024 + (j&1)*512 + t.
  // LDS linear; global source column pre-swizzled (involution) so the
  // swizzled ds_read sees logical [row][k].
  const unsigned short* aS[4];
  const unsigned short* bS[4];
  int lOff[4];
#pragma unroll
  for (int j = 0; j < 4; ++j) {
    int c = ((j >> 1) << 10) + ((j & 1) << 9) + t;
    int row = c >> 3;                            // 128B (=BK*2B) per row
    int sb = ((c & 7) << 4) ^ ((row & 7) << 4);  // swizzled byte col
    aS[j] = Ab + (size_t)(m0 + row) * K + (sb >> 1);
    bS[j] = Bb + (size_t)(n0 + row) * K + (sb >> 1);
    lOff[j] = ((j >> 1) << 14) + ((j & 1) << 13) + (wave << 10);  // uniform
  }

  int ktiles = K >> 6;
  if (CMODE == 2) ktiles = min(ktiles, (by + 1) * 4);  // P==0 past diagonal

  f32x4 acc[8][4] = {};
  const int sx = (fr & 7) << 4;     // read-side swizzle (row&7 == fr&7)
  const int aRowB = wr << 7;        // wave's A row base (0/128)
  const int bRowB = wc << 6;        // wave's B row base (0/64/128/192)

  // prologue: stage K-tile 0 into buf0, drain, enter pipeline
#pragma unroll
  for (int j = 0; j < 4; ++j) { gload_lds16(aS[j], lds + lOff[j]); aS[j] += 64; }
#pragma unroll
  for (int j = 0; j < 4; ++j) { gload_lds16(bS[j], lds + 32768 + lOff[j]); bS[j] += 64; }
  asm volatile("s_waitcnt vmcnt(0)" ::: "memory");
  __builtin_amdgcn_s_barrier();

  for (int kt = 0; kt < ktiles; ++kt) {
    const int cb = (kt & 1) << 16;   // current buffer byte offset
    const int nb = cb ^ 65536;       // next buffer
    const bool pf = (kt + 1 < ktiles);
    const char* la = lds + cb;
    const char* lb = lds + cb + 32768;
#pragma unroll
    for (int q = 0; q < 4; ++q) {
      const int mb = (q & 1) << 2;     // quadrant frag-m base (0/4)
      const int nbf = (q >> 1) << 1;   // quadrant frag-n base (0/2)
      bfx8 af[4][2], bv[2][2];
#pragma unroll
      for (int mi = 0; mi < 4; ++mi) {
        int row = aRowB + ((mb + mi) << 4) + fr;
#pragma unroll
        for (int kk = 0; kk < 2; ++kk)
          af[mi][kk] = *(const bfx8*)(la + row * 128 + (((kk << 6) + (fk << 4)) ^ sx));
      }
#pragma unroll
      for (int ni = 0; ni < 2; ++ni) {
        int row = bRowB + ((nbf + ni) << 4) + fr;
#pragma unroll
        for (int kk = 0; kk < 2; ++kk)
          bv[ni][kk] = *(const bfx8*)(lb + row * 128 + (((kk << 6) + (fk << 4)) ^ sx));
      }
      // prefetch next K-tile: A in phase 0, B in phase 1 (buffer nb's prior
      // content finished its reads last window -> overwrite-safe)
      if (q == 0 && pf) {
#pragma unroll
        for (int j = 0; j < 4; ++j) { gload_lds16(aS[j], lds + nb + lOff[j]); aS[j] += 64; }
      }
      if (q == 1 && pf) {
#pragma unroll
        for (int j = 0; j < 4; ++j) { gload_lds16(bS[j], lds + nb + 32768 + lOff[j]); bS[j] += 64; }
      }
      __builtin_amdgcn_s_barrier();
      asm volatile("s_waitcnt lgkmcnt(0)" ::: "memory");
      __builtin_amdgcn_sched_barrier(0);
      __builtin_amdgcn_s_setprio(1);
#pragma unroll
      for (int kk = 0; kk < 2; ++kk)
#pragma unroll
        for (int mi = 0; mi < 4; ++mi)
#pragma unroll
          for (int ni = 0; ni < 2; ++ni)
            acc[mb + mi][nbf + ni] = __builtin_amdgcn_mfma_f32_16x16x32_bf16(
                af[mi][kk], bv[ni][kk], acc[mb + mi][nbf + ni], 0, 0, 0);
      __builtin_amdgcn_s_setprio(0);
      // drain the next tile's stages only once per K-tile, after ~3 phases
      // of compute cover (never inside the MFMA phases)
      if (q == 3) asm volatile("s_waitcnt vmcnt(0)" ::: "memory");
      __builtin_amdgcn_s_barrier();
    }
  }

  // epilogue: C/D layout col=lane&15, row=(lane>>4)*4+reg (m89-verified)
#pragma unroll
  for (int mf = 0; mf < 8; ++mf) {
#pragma unroll
    for (int nf = 0; nf < 4; ++nf) {
      int r0 = m0 + (wr << 7) + (mf << 4) + (fk << 2);
      int cn = n0 + (wc << 6) + (nf << 4) + fr;
      if (CMODE == 0) {
        unsigned short* C = (unsigned short*)Cv + (size_t)bz * sC;
#pragma unroll
        for (int j = 0; j < 4; ++j)
          C[(size_t)(r0 + j) * N + cn] = f2bf(acc[mf][nf][j]);
      } else {
        float* C = (float*)Cv + (size_t)bz * sC;
#pragma unroll
        for (int j = 0; j < 4; ++j)
          C[(size_t)(r0 + j) * N + cn] = acc[mf][nf][j] * scale;
      }
    }
  }
}

// x fp32 -> bf16, 8 elements/thread
__global__ __launch_bounds__(256) void cvt_x_kernel(
    const float* __restrict__ x, unsigned short* __restrict__ xb)
{
  size_t i = ((size_t)blockIdx.x * 256 + threadIdx.x) * 8;
  float4 a = *(const float4*)(x + i);
  float4 b = *(const float4*)(x + i + 4);
  u16x8 o = {f2bf(a.x), f2bf(a.y), f2bf(a.z), f2bf(a.w),
             f2bf(b.x), f2bf(b.y), f2bf(b.z), f2bf(b.w)};
  *(u16x8*)(xb + i) = o;
}

// W [K][N] fp32 -> Wt [N][K] bf16, 64x64 LDS tile transpose; z picks Wq/Wk/Wv
__global__ __launch_bounds__(256) void cvt_wT_kernel(
    const float* __restrict__ Wq, const float* __restrict__ Wk,
    const float* __restrict__ Wv, unsigned short* __restrict__ Wt)
{
  const float* W = blockIdx.z == 0 ? Wq : (blockIdx.z == 1 ? Wk : Wv);
  unsigned short* out = Wt + (size_t)blockIdx.z * DD * DD;
  __shared__ unsigned short tile[64][65];
  int k0 = blockIdx.y * 64, n0 = blockIdx.x * 64;
#pragma unroll
  for (int i = 0; i < 16; ++i) {
    int idx = threadIdx.x + i * 256;
    int r = idx >> 6, c = idx & 63;
    tile[r][c] = f2bf(W[(size_t)(k0 + r) * DD + n0 + c]);
  }
  __syncthreads();
#pragma unroll
  for (int i = 0; i < 16; ++i) {
    int idx = threadIdx.x + i * 256;
    int r = idx >> 6, c = idx & 63;
    out[(size_t)(n0 + r) * DD + k0 + c] = tile[c][r];
  }
}

// causal row softmax: scores fp32 [b][i][:] -> P bf16 (zeros for j>i)
__global__ __launch_bounds__(256) void softmax_causal(
    const float* __restrict__ Sc, unsigned short* __restrict__ P)
{
  const int i = blockIdx.x, b = blockIdx.y, t = threadIdx.x;
  const float* srow = Sc + ((size_t)b * SS + i) * SS;
  unsigned short* prow = P + ((size_t)b * SS + i) * SS;
  const int j0 = t * 8;
  float4 v0 = *(const float4*)(srow + j0);
  float4 v1 = *(const float4*)(srow + j0 + 4);
  float s[8] = {v0.x, v0.y, v0.z, v0.w, v1.x, v1.y, v1.z, v1.w};
  float mx = -INFINITY;
#pragma unroll
  for (int e = 0; e < 8; ++e) {
    if (j0 + e > i) s[e] = -INFINITY;
    mx = fmaxf(mx, s[e]);
  }
#pragma unroll
  for (int off = 32; off; off >>= 1) mx = fmaxf(mx, __shfl_xor(mx, off));
  __shared__ float red[8];
  if ((t & 63) == 0) red[t >> 6] = mx;
  __syncthreads();
  mx = fmaxf(fmaxf(red[0], red[1]), fmaxf(red[2], red[3]));
  float e8[8];
  float sm = 0.f;
#pragma unroll
  for (int e = 0; e < 8; ++e) {
    e8[e] = (j0 + e <= i) ? __expf(s[e] - mx) : 0.f;
    sm += e8[e];
  }
#pragma unroll
  for (int off = 32; off; off >>= 1) sm += __shfl_xor(sm, off);
  if ((t & 63) == 0) red[4 + (t >> 6)] = sm;
  __syncthreads();
  float inv = 1.0f / (red[4] + red[5] + red[6] + red[7]);
  u16x8 o;
#pragma unroll
  for (int e = 0; e < 8; ++e) o[e] = f2bf(e8[e] * inv);
  *(u16x8*)(prow + j0) = o;
}

extern "C" void kernel_launch(void* const* d_in, const int* in_sizes, int n_in,
                              void* d_out, int out_size, void* d_ws, size_t ws_size,
                              hipStream_t stream)
{
  const float* x  = (const float*)d_in[0];
  const float* Wq = (const float*)d_in[1];
  const float* Wk = (const float*)d_in[2];
  const float* Wv = (const float*)d_in[3];
  float* out = (float*)d_out;

  const size_t MR = (size_t)BB * SS;  // 8192 rows
  unsigned short* xb = (unsigned short*)d_ws;     // [8192][2048] bf16
  unsigned short* Wt = xb + MR * DD;              // 3 x [2048][2048] bf16 (W^T)
  unsigned short* qk = Wt + 3ull * DD * DD;       // q,k each [8192][2048] bf16
  unsigned short* vt = qk + 2ull * MR * DD;       // [4][2048 d][2048 s] bf16
  float* sc = (float*)(vt + (size_t)BB * DD * SS);       // [4][2048][2048] f32
  unsigned short* P = (unsigned short*)(sc + (size_t)BB * SS * SS);  // bf16

  cvt_x_kernel<<<dim3(8192), 256, 0, stream>>>(x, xb);
  cvt_wT_kernel<<<dim3(32, 32, 3), 256, 0, stream>>>(Wq, Wk, Wv, Wt);

  // Q,K projections: [8192,2048] x Wt[N,K]^T; z in {0,1} picks Wq/Wk
  gemm_bt<0><<<dim3(8, 32, 2), 512, 0, stream>>>(
      xb, Wt, qk, DD, DD, 0, (long long)DD * DD, (long long)(MR * DD), 1.f);
  // V projection directly transposed: vt[b] = Wv^T * x[b]^T  (coalesced out)
  gemm_bt<0><<<dim3(8, 8, 4), 512, 0, stream>>>(
      Wt + 2ull * DD * DD, xb, vt, SS, DD,
      0, (long long)(SS * (size_t)DD), (long long)(DD * (size_t)SS), 1.f);

  // scores[b] = q[b] k[b]^T * 1/sqrt(D), fp32, causal block skip
  const float iscale = 1.0f / sqrtf((float)DD);
  gemm_bt<1><<<dim3(8, 8, 4), 512, 0, stream>>>(
      qk, qk + MR * DD, sc, SS, DD,
      (long long)(SS * (size_t)DD), (long long)(SS * (size_t)DD),
      (long long)(SS * (size_t)SS), iscale);

  softmax_causal<<<dim3(SS, BB), 256, 0, stream>>>(sc, P);

  // out[b] = P[b] vt[b]^T, fp32, K-tiles limited to diagonal
  gemm_bt<2><<<dim3(8, 8, 4), 512, 0, stream>>>(
      P, vt, out, DD, SS,
      (long long)(SS * (size_t)SS), (long long)(DD * (size_t)SS),
      (long long)(SS * (size_t)DD), 1.f);
}

// Round 5
// 478.955 us; speedup vs baseline: 1.1628x; 1.0583x over previous
//
#include <hip/hip_runtime.h>
#include <cmath>

typedef __bf16 bfx8 __attribute__((ext_vector_type(8)));
typedef float f32x4 __attribute__((ext_vector_type(4)));
typedef unsigned short u16x8 __attribute__((ext_vector_type(8)));

static constexpr int BB = 4, SS = 2048, DD = 2048;

__device__ __forceinline__ unsigned short f2bf(float f) {
  unsigned u = __builtin_bit_cast(unsigned, f);
  u += 0x7fffu + ((u >> 16) & 1u);
  return (unsigned short)(u >> 16);
}

// global->LDS async copy, 16B per lane. LDS dest wave-uniform; HW adds lane*16.
__device__ __forceinline__ void gload_lds16(const void* g, void* l) {
  __builtin_amdgcn_global_load_lds(
      (__attribute__((address_space(1))) unsigned int*)(g),
      (__attribute__((address_space(3))) unsigned int*)(l),
      16, 0, 0);
}

// -------------------------------------------------------------------------
// C[M,N] = A[M,K] * B_t[N,K] (bf16 in, fp32 acc). 256x256 tile, BK=64,
// 8 waves (2M x 4N), 4-phase K-loop with FRAGMENT REUSE across phases
// (28 ds_read_b128 per wave per K-tile, not 48), double-buffered 2x64KB LDS,
// XOR-swizzle (rule 21), counted drain (vmcnt(0) once per K-tile, phase 3),
// bijective XCD-aware block swizzle (requires gridDim.x==8, nwg%8==0).
// CMODE 0: bf16 out row-major
// CMODE 1: f32 out * scale, skip blocks fully above causal diagonal
// CMODE 2: f32 out, K-tiles truncated at the causal diagonal
// -------------------------------------------------------------------------
template <int CMODE>
__global__ __launch_bounds__(512, 2) void gemm_bt(
    const unsigned short* __restrict__ A, const unsigned short* __restrict__ B,
    void* __restrict__ Cv, int N, int K,
    long long sA, long long sB, long long sC, float scale)
{
  // XCD swizzle: consecutive hw block ids round-robin XCDs; give each XCD a
  // contiguous band of output rows so its L2 holds few A panels.
  const int lid = (blockIdx.y << 3) | blockIdx.x;          // gridDim.x == 8
  const int swz = (lid & 7) * gridDim.y + (lid >> 3);      // bijective
  const int bx = swz & 7, by = swz >> 3, bz = blockIdx.z;
  if (CMODE == 1 && bx > by) return;  // fully above causal diagonal
  const int t = threadIdx.x;
  const int wave = t >> 6, lane = t & 63;
  const int fr = lane & 15, fk = lane >> 4;
  const int wr = wave >> 2;           // M half   (0..1)
  const int wc = wave & 3;            // N quarter (0..3)
  const int m0 = by << 8, n0 = bx << 8;

  __shared__ __align__(16) char lds[131072];  // 2 bufs x (A 32KB + B 32KB)

  const unsigned short* Ab = A + (size_t)bz * sA;
  const unsigned short* Bb = B + (size_t)bz * sB;

  // Staging: thread t covers 16B chunks c = (j>>1)*1024 + (j&1)*512 + t.
  // LDS linear; global source column pre-swizzled (involution) so the
  // swizzled ds_read sees logical [row][k].
  const unsigned short* aS[4];
  const unsigned short* bS[4];
  int lOff[4];
#pragma unroll
  for (int j = 0; j < 4; ++j) {
    int c = ((j >> 1) << 10) + ((j & 1) << 9) + t;
    int row = c >> 3;                            // 128B (=BK*2B) per row
    int sb = ((c & 7) << 4) ^ ((row & 7) << 4);  // swizzled byte col
    aS[j] = Ab + (size_t)(m0 + row) * K + (sb >> 1);
    bS[j] = Bb + (size_t)(n0 + row) * K + (sb >> 1);
    lOff[j] = ((j >> 1) << 14) + ((j & 1) << 13) + (wave << 10);  // uniform
  }

  int ktiles = K >> 6;
  if (CMODE == 2) ktiles = min(ktiles, (by + 1) * 4);  // P==0 past diagonal

  f32x4 acc[8][4] = {};
  const int sx = (fr & 7) << 4;     // read-side swizzle (row&7 == fr&7)
  const int aRowB = wr << 7;        // wave's A row base (0/128)
  const int bRowB = wc << 6;        // wave's B row base (0/64/128/192)

  // prologue: stage K-tile 0 into buf0, drain, enter pipeline
#pragma unroll
  for (int j = 0; j < 4; ++j) { gload_lds16(aS[j], lds + lOff[j]); aS[j] += 64; }
#pragma unroll
  for (int j = 0; j < 4; ++j) { gload_lds16(bS[j], lds + 32768 + lOff[j]); bS[j] += 64; }
  asm volatile("s_waitcnt vmcnt(0)" ::: "memory");
  __builtin_amdgcn_s_barrier();

  // fragment registers held across phases
  bfx8 am[4][2];   // current A m-group (m-frags g*4 .. g*4+3)
  bfx8 bn[2][2];   // current B n-group (n-frags g*2 .. g*2+1)

#define LDA_GRP(la_, mg_)                                                     \
  _Pragma("unroll") for (int mi = 0; mi < 4; ++mi) {                          \
    int row = aRowB + (((mg_) * 4 + mi) << 4) + fr;                           \
    _Pragma("unroll") for (int kk = 0; kk < 2; ++kk)                          \
      am[mi][kk] = *(const bfx8*)((la_) + row * 128 +                         \
                                  (((kk << 6) + (fk << 4)) ^ sx));            \
  }
#define LDB_GRP(lb_, ng_)                                                     \
  _Pragma("unroll") for (int ni = 0; ni < 2; ++ni) {                          \
    int row = bRowB + (((ng_) * 2 + ni) << 4) + fr;                           \
    _Pragma("unroll") for (int kk = 0; kk < 2; ++kk)                          \
      bn[ni][kk] = *(const bfx8*)((lb_) + row * 128 +                         \
                                  (((kk << 6) + (fk << 4)) ^ sx));            \
  }
#define MFMA_QUAD(mg_, ng_)                                                   \
  __builtin_amdgcn_s_setprio(1);                                             \
  _Pragma("unroll") for (int kk = 0; kk < 2; ++kk)                            \
    _Pragma("unroll") for (int mi = 0; mi < 4; ++mi)                          \
      _Pragma("unroll") for (int ni = 0; ni < 2; ++ni)                        \
        acc[(mg_) * 4 + mi][(ng_) * 2 + ni] =                                 \
            __builtin_amdgcn_mfma_f32_16x16x32_bf16(                          \
                am[mi][kk], bn[ni][kk], acc[(mg_) * 4 + mi][(ng_) * 2 + ni],  \
                0, 0, 0);                                                     \
  __builtin_amdgcn_s_setprio(0);
#define PHASE_SYNC()                                                          \
  __builtin_amdgcn_s_barrier();                                               \
  asm volatile("s_waitcnt lgkmcnt(0)" ::: "memory");                          \
  __builtin_amdgcn_sched_barrier(0);

  for (int kt = 0; kt < ktiles; ++kt) {
    const int cb = (kt & 1) << 16;   // current buffer byte offset
    const int nb = cb ^ 65536;       // next buffer
    const bool pf = (kt + 1 < ktiles);
    const char* la = lds + cb;
    const char* lb = lds + cb + 32768;

    // phase 0: read A-grp0 + B-grp0 (12), prefetch next A, MFMA (0,0)
    LDA_GRP(la, 0); LDB_GRP(lb, 0);
    if (pf) {
#pragma unroll
      for (int j = 0; j < 4; ++j) { gload_lds16(aS[j], lds + nb + lOff[j]); aS[j] += 64; }
    }
    PHASE_SYNC(); MFMA_QUAD(0, 0);
    __builtin_amdgcn_s_barrier();

    // phase 1: read B-grp1 (4) [A-grp0 held], prefetch next B, MFMA (0,1)
    LDB_GRP(lb, 1);
    if (pf) {
#pragma unroll
      for (int j = 0; j < 4; ++j) { gload_lds16(bS[j], lds + nb + 32768 + lOff[j]); bS[j] += 64; }
    }
    PHASE_SYNC(); MFMA_QUAD(0, 1);
    __builtin_amdgcn_s_barrier();

    // phase 2: read A-grp1 (8) [B-grp1 held], MFMA (1,1)
    LDA_GRP(la, 1);
    PHASE_SYNC(); MFMA_QUAD(1, 1);
    __builtin_amdgcn_s_barrier();

    // phase 3: re-read B-grp0 (4) [A-grp1 held], MFMA (1,0), drain stages
    LDB_GRP(lb, 0);
    PHASE_SYNC(); MFMA_QUAD(1, 0);
    asm volatile("s_waitcnt vmcnt(0)" ::: "memory");
    __builtin_amdgcn_s_barrier();
  }
#undef LDA_GRP
#undef LDB_GRP
#undef MFMA_QUAD
#undef PHASE_SYNC

  // epilogue: C/D layout col=lane&15, row=(lane>>4)*4+reg (m89-verified)
#pragma unroll
  for (int mf = 0; mf < 8; ++mf) {
#pragma unroll
    for (int nf = 0; nf < 4; ++nf) {
      int r0 = m0 + (wr << 7) + (mf << 4) + (fk << 2);
      int cn = n0 + (wc << 6) + (nf << 4) + fr;
      if (CMODE == 0) {
        unsigned short* C = (unsigned short*)Cv + (size_t)bz * sC;
#pragma unroll
        for (int j = 0; j < 4; ++j)
          C[(size_t)(r0 + j) * N + cn] = f2bf(acc[mf][nf][j]);
      } else {
        float* C = (float*)Cv + (size_t)bz * sC;
#pragma unroll
        for (int j = 0; j < 4; ++j)
          C[(size_t)(r0 + j) * N + cn] = acc[mf][nf][j] * scale;
      }
    }
  }
}

// x fp32 -> bf16, 8 elements/thread
__global__ __launch_bounds__(256) void cvt_x_kernel(
    const float* __restrict__ x, unsigned short* __restrict__ xb)
{
  size_t i = ((size_t)blockIdx.x * 256 + threadIdx.x) * 8;
  float4 a = *(const float4*)(x + i);
  float4 b = *(const float4*)(x + i + 4);
  u16x8 o = {f2bf(a.x), f2bf(a.y), f2bf(a.z), f2bf(a.w),
             f2bf(b.x), f2bf(b.y), f2bf(b.z), f2bf(b.w)};
  *(u16x8*)(xb + i) = o;
}

// W [K][N] fp32 -> Wt [N][K] bf16, 64x64 LDS tile transpose; z picks Wq/Wk/Wv
__global__ __launch_bounds__(256) void cvt_wT_kernel(
    const float* __restrict__ Wq, const float* __restrict__ Wk,
    const float* __restrict__ Wv, unsigned short* __restrict__ Wt)
{
  const float* W = blockIdx.z == 0 ? Wq : (blockIdx.z == 1 ? Wk : Wv);
  unsigned short* out = Wt + (size_t)blockIdx.z * DD * DD;
  __shared__ unsigned short tile[64][65];
  int k0 = blockIdx.y * 64, n0 = blockIdx.x * 64;
#pragma unroll
  for (int i = 0; i < 16; ++i) {
    int idx = threadIdx.x + i * 256;
    int r = idx >> 6, c = idx & 63;
    tile[r][c] = f2bf(W[(size_t)(k0 + r) * DD + n0 + c]);
  }
  __syncthreads();
#pragma unroll
  for (int i = 0; i < 16; ++i) {
    int idx = threadIdx.x + i * 256;
    int r = idx >> 6, c = idx & 63;
    out[(size_t)(n0 + r) * DD + k0 + c] = tile[c][r];
  }
}

// causal row softmax: scores fp32 [b][i][:] -> P bf16 (zeros for j>i)
__global__ __launch_bounds__(256) void softmax_causal(
    const float* __restrict__ Sc, unsigned short* __restrict__ P)
{
  const int i = blockIdx.x, b = blockIdx.y, t = threadIdx.x;
  const float* srow = Sc + ((size_t)b * SS + i) * SS;
  unsigned short* prow = P + ((size_t)b * SS + i) * SS;
  const int j0 = t * 8;
  float4 v0 = *(const float4*)(srow + j0);
  float4 v1 = *(const float4*)(srow + j0 + 4);
  float s[8] = {v0.x, v0.y, v0.z, v0.w, v1.x, v1.y, v1.z, v1.w};
  float mx = -INFINITY;
#pragma unroll
  for (int e = 0; e < 8; ++e) {
    if (j0 + e > i) s[e] = -INFINITY;
    mx = fmaxf(mx, s[e]);
  }
#pragma unroll
  for (int off = 32; off; off >>= 1) mx = fmaxf(mx, __shfl_xor(mx, off));
  __shared__ float red[8];
  if ((t & 63) == 0) red[t >> 6] = mx;
  __syncthreads();
  mx = fmaxf(fmaxf(red[0], red[1]), fmaxf(red[2], red[3]));
  float e8[8];
  float sm = 0.f;
#pragma unroll
  for (int e = 0; e < 8; ++e) {
    e8[e] = (j0 + e <= i) ? __expf(s[e] - mx) : 0.f;
    sm += e8[e];
  }
#pragma unroll
  for (int off = 32; off; off >>= 1) sm += __shfl_xor(sm, off);
  if ((t & 63) == 0) red[4 + (t >> 6)] = sm;
  __syncthreads();
  float inv = 1.0f / (red[4] + red[5] + red[6] + red[7]);
  u16x8 o;
#pragma unroll
  for (int e = 0; e < 8; ++e) o[e] = f2bf(e8[e] * inv);
  *(u16x8*)(prow + j0) = o;
}

extern "C" void kernel_launch(void* const* d_in, const int* in_sizes, int n_in,
                              void* d_out, int out_size, void* d_ws, size_t ws_size,
                              hipStream_t stream)
{
  const float* x  = (const float*)d_in[0];
  const float* Wq = (const float*)d_in[1];
  const float* Wk = (const float*)d_in[2];
  const float* Wv = (const float*)d_in[3];
  float* out = (float*)d_out;

  const size_t MR = (size_t)BB * SS;  // 8192 rows
  unsigned short* xb = (unsigned short*)d_ws;     // [8192][2048] bf16
  unsigned short* Wt = xb + MR * DD;              // 3 x [2048][2048] bf16 (W^T)
  unsigned short* qk = Wt + 3ull * DD * DD;       // q,k each [8192][2048] bf16
  unsigned short* vt = qk + 2ull * MR * DD;       // [4][2048 d][2048 s] bf16
  float* sc = (float*)(vt + (size_t)BB * DD * SS);       // [4][2048][2048] f32
  unsigned short* P = (unsigned short*)(sc + (size_t)BB * SS * SS);  // bf16

  cvt_x_kernel<<<dim3(8192), 256, 0, stream>>>(x, xb);
  cvt_wT_kernel<<<dim3(32, 32, 3), 256, 0, stream>>>(Wq, Wk, Wv, Wt);

  // Q,K projections: [8192,2048] x Wt[N,K]^T; z in {0,1} picks Wq/Wk
  gemm_bt<0><<<dim3(8, 32, 2), 512, 0, stream>>>(
      xb, Wt, qk, DD, DD, 0, (long long)DD * DD, (long long)(MR * DD), 1.f);
  // V projection directly transposed: vt[b] = Wv^T * x[b]^T  (coalesced out)
  gemm_bt<0><<<dim3(8, 8, 4), 512, 0, stream>>>(
      Wt + 2ull * DD * DD, xb, vt, SS, DD,
      0, (long long)(SS * (size_t)DD), (long long)(DD * (size_t)SS), 1.f);

  // scores[b] = q[b] k[b]^T * 1/sqrt(D), fp32, causal block skip
  const float iscale = 1.0f / sqrtf((float)DD);
  gemm_bt<1><<<dim3(8, 8, 4), 512, 0, stream>>>(
      qk, qk + MR * DD, sc, SS, DD,
      (long long)(SS * (size_t)DD), (long long)(SS * (size_t)DD),
      (long long)(SS * (size_t)SS), iscale);

  softmax_causal<<<dim3(SS, BB), 256, 0, stream>>>(sc, P);

  // out[b] = P[b] vt[b]^T, fp32, K-tiles limited to diagonal
  gemm_bt<2><<<dim3(8, 8, 4), 512, 0, stream>>>(
      P, vt, out, DD, SS,
      (long long)(SS * (size_t)SS), (long long)(DD * (size_t)SS),
      (long long)(SS * (size_t)DD), 1.f);
}

// Round 7
// 471.969 us; speedup vs baseline: 1.1800x; 1.0148x over previous
//
#include <hip/hip_runtime.h>
#include <cmath>

typedef __bf16 bfx8 __attribute__((ext_vector_type(8)));
typedef float f32x4 __attribute__((ext_vector_type(4)));
typedef unsigned short u16x8 __attribute__((ext_vector_type(8)));

static constexpr int BB = 4, SS = 2048, DD = 2048;

__device__ __forceinline__ unsigned short f2bf(float f) {
  unsigned u = __builtin_bit_cast(unsigned, f);
  u += 0x7fffu + ((u >> 16) & 1u);
  return (unsigned short)(u >> 16);
}

// global->LDS async copy, 16B per lane. LDS dest wave-uniform; HW adds lane*16.
__device__ __forceinline__ void gload_lds16(const void* g, void* l) {
  __builtin_amdgcn_global_load_lds(
      (__attribute__((address_space(1))) unsigned int*)(g),
      (__attribute__((address_space(3))) unsigned int*)(l),
      16, 0, 0);
}

// -------------------------------------------------------------------------
// C[M,N] = A[M,K] * B_t[N,K] (bf16 in, fp32 acc). 256x256 tile, BK=64,
// 8 waves (2M x 4N), free-running K-loop: ONE barrier per K-tile (double
// buffer makes intra-tile barriers unnecessary), minimal 24 ds_read_b128
// per wave per tile (B-frags held, A streamed), compiler-scheduled waits,
// XOR-swizzled LDS (rule 21), XCD-aware bijective block swizzle.
// CMODE 0: bf16 out row-major
// CMODE 1: f32 out * scale, skip blocks fully above causal diagonal
// CMODE 2: f32 out, K-tiles truncated at the causal diagonal
// -------------------------------------------------------------------------
template <int CMODE>
__global__ __launch_bounds__(512, 2) void gemm_bt(
    const unsigned short* __restrict__ A, const unsigned short* __restrict__ B,
    void* __restrict__ Cv, int N, int K,
    long long sA, long long sB, long long sC, float scale)
{
  // XCD swizzle: consecutive hw ids round-robin the 8 XCDs; remap so each
  // XCD owns a contiguous band of output rows (L2 reuse of A panels).
  const int lid = (blockIdx.y << 3) | blockIdx.x;          // gridDim.x == 8
  const int swz = (lid & 7) * gridDim.y + (lid >> 3);      // bijective
  const int bx = swz & 7, by = swz >> 3, bz = blockIdx.z;
  if (CMODE == 1 && bx > by) return;  // fully above causal diagonal
  const int t = threadIdx.x;
  const int wave = t >> 6, lane = t & 63;
  const int fr = lane & 15, fk = lane >> 4;
  const int wr = wave >> 2;           // M half   (0..1)
  const int wc = wave & 3;            // N quarter (0..3)
  const int m0 = by << 8, n0 = bx << 8;

  __shared__ __align__(16) char lds[131072];  // 2 bufs x (A 32KB + B 32KB)

  const unsigned short* Ab = A + (size_t)bz * sA;
  const unsigned short* Bb = B + (size_t)bz * sB;

  // Staging: thread t covers 16B chunks c = (j>>1)*1024 + (j&1)*512 + t.
  // LDS linear; global source column pre-swizzled (involution) so the
  // swizzled ds_read sees logical [row][k].
  const unsigned short* aS[4];
  const unsigned short* bS[4];
  int lOff[4];
#pragma unroll
  for (int j = 0; j < 4; ++j) {
    int c = ((j >> 1) << 10) + ((j & 1) << 9) + t;
    int row = c >> 3;                            // 128B (=BK*2B) per row
    int sb = ((c & 7) << 4) ^ ((row & 7) << 4);  // swizzled byte col
    aS[j] = Ab + (size_t)(m0 + row) * K + (sb >> 1);
    bS[j] = Bb + (size_t)(n0 + row) * K + (sb >> 1);
    lOff[j] = ((j >> 1) << 14) + ((j & 1) << 13) + (wave << 10);  // uniform
  }

  int ktiles = K >> 6;
  if (CMODE == 2) ktiles = min(ktiles, (by + 1) * 4);  // P==0 past diagonal

  f32x4 acc[8][4] = {};
  const int sx = (fr & 7) << 4;     // read-side swizzle (row&7 == fr&7)
  const int aRowB = wr << 7;        // wave's A row base (0/128)
  const int bRowB = wc << 6;        // wave's B row base (0/64/128/192)

  // prologue: stage K-tile 0 into buf0, drain, enter loop
#pragma unroll
  for (int j = 0; j < 4; ++j) { gload_lds16(aS[j], lds + lOff[j]); aS[j] += 64; }
#pragma unroll
  for (int j = 0; j < 4; ++j) { gload_lds16(bS[j], lds + 32768 + lOff[j]); bS[j] += 64; }
  asm volatile("s_waitcnt vmcnt(0)" ::: "memory");
  __builtin_amdgcn_s_barrier();

  for (int kt = 0; kt < ktiles; ++kt) {
    const int cb = (kt & 1) << 16;
    const int nb = cb ^ 65536;
    const char* la = lds + cb;
    const char* lb = la + 32768;

    // issue next tile's staging first: HBM latency hides under this tile's
    // compute; writes go to the buffer whose reads finished at tile kt-1.
    if (kt + 1 < ktiles) {
#pragma unroll
      for (int j = 0; j < 4; ++j) { gload_lds16(aS[j], lds + nb + lOff[j]); aS[j] += 64; }
#pragma unroll
      for (int j = 0; j < 4; ++j) { gload_lds16(bS[j], lds + nb + 32768 + lOff[j]); bS[j] += 64; }
    }

    // hold all 8 B fragments; stream A; each fragment read exactly once.
    bfx8 bv[4][2];
#pragma unroll
    for (int ni = 0; ni < 4; ++ni) {
      int row = bRowB + (ni << 4) + fr;
#pragma unroll
      for (int kk = 0; kk < 2; ++kk)
        bv[ni][kk] = *(const bfx8*)(lb + row * 128 + ((((kk << 6) | (fk << 4))) ^ sx));
    }
    __builtin_amdgcn_s_setprio(1);
#pragma unroll
    for (int mi = 0; mi < 8; ++mi) {
      int row = aRowB + (mi << 4) + fr;
      bfx8 a0 = *(const bfx8*)(la + row * 128 + (((fk << 4)) ^ sx));
      bfx8 a1 = *(const bfx8*)(la + row * 128 + ((64 | (fk << 4)) ^ sx));
#pragma unroll
      for (int ni = 0; ni < 4; ++ni)
        acc[mi][ni] = __builtin_amdgcn_mfma_f32_16x16x32_bf16(a0, bv[ni][0], acc[mi][ni], 0, 0, 0);
#pragma unroll
      for (int ni = 0; ni < 4; ++ni)
        acc[mi][ni] = __builtin_amdgcn_mfma_f32_16x16x32_bf16(a1, bv[ni][1], acc[mi][ni], 0, 0, 0);
    }
    __builtin_amdgcn_s_setprio(0);

    // single per-tile sync: staging landed (vmcnt) + all reads consumed
    // (lgkm; compiler already drained via use) + block-wide barrier.
    asm volatile("s_waitcnt vmcnt(0) lgkmcnt(0)" ::: "memory");
    __builtin_amdgcn_s_barrier();
  }

  // epilogue: C/D layout col=lane&15, row=(lane>>4)*4+reg (m89-verified)
#pragma unroll
  for (int mf = 0; mf < 8; ++mf) {
#pragma unroll
    for (int nf = 0; nf < 4; ++nf) {
      int r0 = m0 + (wr << 7) + (mf << 4) + (fk << 2);
      int cn = n0 + (wc << 6) + (nf << 4) + fr;
      if (CMODE == 0) {
        unsigned short* C = (unsigned short*)Cv + (size_t)bz * sC;
#pragma unroll
        for (int j = 0; j < 4; ++j)
          C[(size_t)(r0 + j) * N + cn] = f2bf(acc[mf][nf][j]);
      } else {
        float* C = (float*)Cv + (size_t)bz * sC;
#pragma unroll
        for (int j = 0; j < 4; ++j)
          C[(size_t)(r0 + j) * N + cn] = acc[mf][nf][j] * scale;
      }
    }
  }
}

// x fp32 -> bf16, 8 elements/thread
__global__ __launch_bounds__(256) void cvt_x_kernel(
    const float* __restrict__ x, unsigned short* __restrict__ xb)
{
  size_t i = ((size_t)blockIdx.x * 256 + threadIdx.x) * 8;
  float4 a = *(const float4*)(x + i);
  float4 b = *(const float4*)(x + i + 4);
  u16x8 o = {f2bf(a.x), f2bf(a.y), f2bf(a.z), f2bf(a.w),
             f2bf(b.x), f2bf(b.y), f2bf(b.z), f2bf(b.w)};
  *(u16x8*)(xb + i) = o;
}

// W [K][N] fp32 -> Wt [N][K] bf16, 64x64 LDS tile transpose; z picks Wq/Wk/Wv
__global__ __launch_bounds__(256) void cvt_wT_kernel(
    const float* __restrict__ Wq, const float* __restrict__ Wk,
    const float* __restrict__ Wv, unsigned short* __restrict__ Wt)
{
  const float* W = blockIdx.z == 0 ? Wq : (blockIdx.z == 1 ? Wk : Wv);
  unsigned short* out = Wt + (size_t)blockIdx.z * DD * DD;
  __shared__ unsigned short tile[64][65];
  int k0 = blockIdx.y * 64, n0 = blockIdx.x * 64;
#pragma unroll
  for (int i = 0; i < 16; ++i) {
    int idx = threadIdx.x + i * 256;
    int r = idx >> 6, c = idx & 63;
    tile[r][c] = f2bf(W[(size_t)(k0 + r) * DD + n0 + c]);
  }
  __syncthreads();
#pragma unroll
  for (int i = 0; i < 16; ++i) {
    int idx = threadIdx.x + i * 256;
    int r = idx >> 6, c = idx & 63;
    out[(size_t)(n0 + r) * DD + k0 + c] = tile[c][r];
  }
}

// causal row softmax: scores fp32 [b][i][:] -> P bf16 (zeros for j>i)
__global__ __launch_bounds__(256) void softmax_causal(
    const float* __restrict__ Sc, unsigned short* __restrict__ P)
{
  const int i = blockIdx.x, b = blockIdx.y, t = threadIdx.x;
  const float* srow = Sc + ((size_t)b * SS + i) * SS;
  unsigned short* prow = P + ((size_t)b * SS + i) * SS;
  const int j0 = t * 8;
  float4 v0 = *(const float4*)(srow + j0);
  float4 v1 = *(const float4*)(srow + j0 + 4);
  float s[8] = {v0.x, v0.y, v0.z, v0.w, v1.x, v1.y, v1.z, v1.w};
  float mx = -INFINITY;
#pragma unroll
  for (int e = 0; e < 8; ++e) {
    if (j0 + e > i) s[e] = -INFINITY;
    mx = fmaxf(mx, s[e]);
  }
#pragma unroll
  for (int off = 32; off; off >>= 1) mx = fmaxf(mx, __shfl_xor(mx, off));
  __shared__ float red[8];
  if ((t & 63) == 0) red[t >> 6] = mx;
  __syncthreads();
  mx = fmaxf(fmaxf(red[0], red[1]), fmaxf(red[2], red[3]));
  float e8[8];
  float sm = 0.f;
#pragma unroll
  for (int e = 0; e < 8; ++e) {
    e8[e] = (j0 + e <= i) ? __expf(s[e] - mx) : 0.f;
    sm += e8[e];
  }
#pragma unroll
  for (int off = 32; off; off >>= 1) sm += __shfl_xor(sm, off);
  if ((t & 63) == 0) red[4 + (t >> 6)] = sm;
  __syncthreads();
  float inv = 1.0f / (red[4] + red[5] + red[6] + red[7]);
  u16x8 o;
#pragma unroll
  for (int e = 0; e < 8; ++e) o[e] = f2bf(e8[e] * inv);
  *(u16x8*)(prow + j0) = o;
}

extern "C" void kernel_launch(void* const* d_in, const int* in_sizes, int n_in,
                              void* d_out, int out_size, void* d_ws, size_t ws_size,
                              hipStream_t stream)
{
  const float* x  = (const float*)d_in[0];
  const float* Wq = (const float*)d_in[1];
  const float* Wk = (const float*)d_in[2];
  const float* Wv = (const float*)d_in[3];
  float* out = (float*)d_out;

  const size_t MR = (size_t)BB * SS;  // 8192 rows
  unsigned short* xb = (unsigned short*)d_ws;     // [8192][2048] bf16
  unsigned short* Wt = xb + MR * DD;              // 3 x [2048][2048] bf16 (W^T)
  unsigned short* qk = Wt + 3ull * DD * DD;       // q,k each [8192][2048] bf16
  unsigned short* vt = qk + 2ull * MR * DD;       // [4][2048 d][2048 s] bf16
  float* sc = (float*)(vt + (size_t)BB * DD * SS);       // [4][2048][2048] f32
  unsigned short* P = (unsigned short*)(sc + (size_t)BB * SS * SS);  // bf16

  cvt_x_kernel<<<dim3(8192), 256, 0, stream>>>(x, xb);
  cvt_wT_kernel<<<dim3(32, 32, 3), 256, 0, stream>>>(Wq, Wk, Wv, Wt);

  // Q,K projections: [8192,2048] x Wt[N,K]^T; z in {0,1} picks Wq/Wk
  gemm_bt<0><<<dim3(8, 32, 2), 512, 0, stream>>>(
      xb, Wt, qk, DD, DD, 0, (long long)DD * DD, (long long)(MR * DD), 1.f);
  // V projection directly transposed: vt[b] = Wv^T * x[b]^T  (coalesced out)
  gemm_bt<0><<<dim3(8, 8, 4), 512, 0, stream>>>(
      Wt + 2ull * DD * DD, xb, vt, SS, DD,
      0, (long long)(SS * (size_t)DD), (long long)(DD * (size_t)SS), 1.f);

  // scores[b] = q[b] k[b]^T * 1/sqrt(D), fp32, causal block skip
  const float iscale = 1.0f / sqrtf((float)DD);
  gemm_bt<1><<<dim3(8, 8, 4), 512, 0, stream>>>(
      qk, qk + MR * DD, sc, SS, DD,
      (long long)(SS * (size_t)DD), (long long)(SS * (size_t)DD),
      (long long)(SS * (size_t)SS), iscale);

  softmax_causal<<<dim3(SS, BB), 256, 0, stream>>>(sc, P);

  // out[b] = P[b] vt[b]^T, fp32, K-tiles limited to diagonal
  gemm_bt<2><<<dim3(8, 8, 4), 512, 0, stream>>>(
      P, vt, out, DD, SS,
      (long long)(SS * (size_t)SS), (long long)(DD * (size_t)SS),
      (long long)(SS * (size_t)DD), 1.f);
}